// Round 1
// baseline (2975.957 us; speedup 1.0000x reference)
//
#include <hip/hip_runtime.h>

#define D    256
#define KCB  16384
#define BN   16384
#define TILE 64

// ---------------------------------------------------------------------------
// Kernel 1: emb[k][d] = sum_j ew[k][j] * pw[d][j] + pb[d]   (torch Linear)
// Also s[k] = ||emb[k]||^2 (fused block reduction).
// One block per codebook row k; 256 threads = one per d.
// ---------------------------------------------------------------------------
__global__ __launch_bounds__(256) void proj_kernel(
    const float* __restrict__ ew, const float* __restrict__ pw,
    const float* __restrict__ pb, float* __restrict__ emb,
    float* __restrict__ s)
{
    __shared__ float row[D];
    __shared__ float wsum[4];
    const int k = blockIdx.x;
    const int d = threadIdx.x;

    row[d] = ew[(size_t)k * D + d];
    __syncthreads();

    const float* pwr = pw + (size_t)d * D;
    float sum = 0.f;
#pragma unroll
    for (int j = 0; j < D; j += 4) {
        float4 a = *(const float4*)(&row[j]);   // broadcast, no conflict
        float4 b = *(const float4*)(&pwr[j]);   // L2-resident (pw = 256 KB)
        sum = fmaf(a.x, b.x, sum);
        sum = fmaf(a.y, b.y, sum);
        sum = fmaf(a.z, b.z, sum);
        sum = fmaf(a.w, b.w, sum);
    }
    const float e = sum + pb[d];
    emb[(size_t)k * D + d] = e;

    // block reduction of e*e -> s[k]
    float sq = e * e;
#pragma unroll
    for (int m = 1; m < 64; m <<= 1) sq += __shfl_xor(sq, m);
    if ((d & 63) == 0) wsum[d >> 6] = sq;
    __syncthreads();
    if (d == 0) s[k] = (wsum[0] + wsum[1]) + (wsum[2] + wsum[3]);
}

// ---------------------------------------------------------------------------
// Kernel 2: fused distance + argmin.
// score(r,k) = s[k] - 2 * dot(z_r, e_k)   (|z_r|^2 dropped: constant per row)
// Block = 256 threads handles a 64-row x all-K strip.
//   thread (tr,tc): tr = tid>>4 owns rows tr*4..tr*4+3, tc = tid&15 owns
//   k-columns tc*4..tc*4+3 of each 64-wide k tile. 4x4 register blocking.
// LDS: Z tile 64x256 f32 (64 KB) + E tile 64x256 f32 (64 KB), both stored as
// float4 slots with XOR swizzle  slot = c ^ ((row>>2)&7)  to kill the 16-way
// bank conflict on the E-operand read (stride-1024B rows).
// ---------------------------------------------------------------------------
__global__ __launch_bounds__(256) void argmin_kernel(
    const float* __restrict__ z, const float* __restrict__ emb,
    const float* __restrict__ s, int* __restrict__ qidx)
{
    __shared__ float4 Zs[TILE][64];
    __shared__ float4 Es[TILE][64];
    __shared__ float  Ss[TILE];

    const int tid = threadIdx.x;
    const int tc  = tid & 15;
    const int tr  = tid >> 4;
    const size_t r0 = (size_t)blockIdx.x * TILE;

    // stage Z tile (coalesced float4, swizzled store)
    {
        const float4* zg = (const float4*)(z + r0 * D);
#pragma unroll
        for (int i = 0; i < TILE * 64; i += 256) {
            const int idx = i + tid;
            const int r = idx >> 6, c = idx & 63;
            Zs[r][c ^ ((r >> 2) & 7)] = zg[idx];
        }
    }

    float bestv[4];
    int   bestk[4];
#pragma unroll
    for (int a = 0; a < 4; ++a) { bestv[a] = 3.4e38f; bestk[a] = 0; }

    const int zswz = tr & 7;   // (row>>2)&7 is tr for all 4 owned rows
    const int eswz = tc & 7;   // likewise tc for all 4 owned k-columns

    for (int kt = 0; kt < KCB; kt += TILE) {
        __syncthreads();
        {
            const float4* eg = (const float4*)(emb + (size_t)kt * D);
#pragma unroll
            for (int i = 0; i < TILE * 64; i += 256) {
                const int idx = i + tid;
                const int r = idx >> 6, c = idx & 63;
                Es[r][c ^ ((r >> 2) & 7)] = eg[idx];
            }
            if (tid < TILE) Ss[tid] = s[kt + tid];
        }
        __syncthreads();

        float acc[4][4];
#pragma unroll
        for (int a = 0; a < 4; ++a)
#pragma unroll
            for (int b = 0; b < 4; ++b) acc[a][b] = 0.f;

        for (int c = 0; c < 64; ++c) {
            const int czs = c ^ zswz;
            const int ces = c ^ eswz;
            float4 zv[4], ev[4];
#pragma unroll
            for (int a = 0; a < 4; ++a) zv[a] = Zs[tr * 4 + a][czs];
#pragma unroll
            for (int b = 0; b < 4; ++b) ev[b] = Es[tc * 4 + b][ces];
#pragma unroll
            for (int a = 0; a < 4; ++a)
#pragma unroll
                for (int b = 0; b < 4; ++b) {
                    acc[a][b] = fmaf(zv[a].x, ev[b].x, acc[a][b]);
                    acc[a][b] = fmaf(zv[a].y, ev[b].y, acc[a][b]);
                    acc[a][b] = fmaf(zv[a].z, ev[b].z, acc[a][b]);
                    acc[a][b] = fmaf(zv[a].w, ev[b].w, acc[a][b]);
                }
        }

#pragma unroll
        for (int a = 0; a < 4; ++a)
#pragma unroll
            for (int b = 0; b < 4; ++b) {
                const int   kk = kt + tc * 4 + b;
                const float v  = fmaf(-2.f, acc[a][b], Ss[tc * 4 + b]);
                if (v < bestv[a] || (v == bestv[a] && kk < bestk[a])) {
                    bestv[a] = v; bestk[a] = kk;
                }
            }
    }

    // reduce (min, argmin) across the 16 tc-lanes sharing each row
#pragma unroll
    for (int a = 0; a < 4; ++a) {
        float v = bestv[a];
        int   k = bestk[a];
#pragma unroll
        for (int m = 1; m < 16; m <<= 1) {
            const float ov = __shfl_xor(v, m);
            const int   ok = __shfl_xor(k, m);
            if (ov < v || (ov == v && ok < k)) { v = ov; k = ok; }
        }
        if (tc == 0) qidx[r0 + tr * 4 + a] = k;
    }
}

// ---------------------------------------------------------------------------
// Kernel 3: gather quantized rows + emit indices as float.
// ---------------------------------------------------------------------------
__global__ __launch_bounds__(256) void gather_kernel(
    const float* __restrict__ emb, const int* __restrict__ qidx,
    float* __restrict__ outq, float* __restrict__ outidx)
{
    const int row = blockIdx.x;
    const int d   = threadIdx.x;
    const int k   = qidx[row];
    outq[(size_t)row * D + d] = emb[(size_t)k * D + d];
    if (d == 0) outidx[row] = (float)k;
}

extern "C" void kernel_launch(void* const* d_in, const int* in_sizes, int n_in,
                              void* d_out, int out_size, void* d_ws, size_t ws_size,
                              hipStream_t stream)
{
    const float* z  = (const float*)d_in[0];
    const float* ew = (const float*)d_in[1];
    const float* pw = (const float*)d_in[2];
    const float* pb = (const float*)d_in[3];

    float* out      = (float*)d_out;
    float* out_z    = out;                           // (B,N,D)
    float* out_emb  = out + (size_t)BN * D;          // (K,D)
    float* out_q    = out + 2 * (size_t)BN * D;      // (B,N,D)
    float* out_idx  = out + 3 * (size_t)BN * D;      // (B,N) as float

    float* s    = (float*)d_ws;                      // 16384 f32  (64 KB)
    int*  qidx  = (int*)((char*)d_ws + 65536);       // 16384 i32  (64 KB)

    // output 0: z passthrough
    hipMemcpyAsync(out_z, z, (size_t)BN * D * sizeof(float),
                   hipMemcpyDeviceToDevice, stream);

    // output 1: emb (also argmin input), + s[k]
    proj_kernel<<<KCB, 256, 0, stream>>>(ew, pw, pb, out_emb, s);

    // indices
    argmin_kernel<<<BN / TILE, 256, 0, stream>>>(z, out_emb, s, qidx);

    // outputs 2,3
    gather_kernel<<<BN, 256, 0, stream>>>(out_emb, qidx, out_q, out_idx);
}

// Round 2
// 1233.135 us; speedup vs baseline: 2.4133x; 2.4133x over previous
//
#include <hip/hip_runtime.h>
#include <hip/hip_bf16.h>

#define D      256
#define KCB    16384
#define BNROWS 16384

typedef __attribute__((ext_vector_type(8))) short short8;   // 8 bf16 = 4 VGPR
typedef __attribute__((ext_vector_type(4))) float f32x4;

// async global->LDS, 16B per lane; LDS dest = wave-uniform base + lane*16
__device__ __forceinline__ void gload_lds16(const void* g, void* l) {
    __builtin_amdgcn_global_load_lds(
        (const __attribute__((address_space(1))) void*)g,
        (__attribute__((address_space(3))) void*)l, 16, 0, 0);
}

__device__ __forceinline__ void bf16split(float x, unsigned short& hi, unsigned short& lo) {
    __hip_bfloat16 h = __float2bfloat16(x);
    float hf = __bfloat162float(h);
    __hip_bfloat16 l = __float2bfloat16(x - hf);
    hi = *(unsigned short*)&h;
    lo = *(unsigned short*)&l;
}

// ---------------------------------------------------------------------------
// z -> (z_hi, z_lo) bf16 planes.  One float4 per thread.
// ---------------------------------------------------------------------------
__global__ __launch_bounds__(256) void zsplit_kernel(
    const float* __restrict__ z,
    unsigned short* __restrict__ zhi, unsigned short* __restrict__ zlo)
{
    const int i = blockIdx.x * 256 + threadIdx.x;
    float4 v = ((const float4*)z)[i];
    ushort4 h, l;
    bf16split(v.x, h.x, l.x);
    bf16split(v.y, h.y, l.y);
    bf16split(v.z, h.z, l.z);
    bf16split(v.w, h.w, l.w);
    ((ushort4*)zhi)[i] = h;
    ((ushort4*)zlo)[i] = l;
}

// ---------------------------------------------------------------------------
// emb = ew @ pw^T + pb (fp32 output), fused: ||e||^2 and bf16 hi/lo planes.
// One block per codebook row (known-good from round 1).
// ---------------------------------------------------------------------------
__global__ __launch_bounds__(256) void proj_kernel(
    const float* __restrict__ ew, const float* __restrict__ pw,
    const float* __restrict__ pb, float* __restrict__ emb,
    float* __restrict__ s,
    unsigned short* __restrict__ ehi, unsigned short* __restrict__ elo)
{
    __shared__ float row[D];
    __shared__ float wsum[4];
    const int k = blockIdx.x;
    const int d = threadIdx.x;

    row[d] = ew[(size_t)k * D + d];
    __syncthreads();

    const float* pwr = pw + (size_t)d * D;
    float sum = 0.f;
#pragma unroll
    for (int j = 0; j < D; j += 4) {
        float4 a = *(const float4*)(&row[j]);
        float4 b = *(const float4*)(&pwr[j]);
        sum = fmaf(a.x, b.x, sum);
        sum = fmaf(a.y, b.y, sum);
        sum = fmaf(a.z, b.z, sum);
        sum = fmaf(a.w, b.w, sum);
    }
    const float e = sum + pb[d];
    emb[(size_t)k * D + d] = e;

    unsigned short hb, lb;
    bf16split(e, hb, lb);
    ehi[(size_t)k * D + d] = hb;
    elo[(size_t)k * D + d] = lb;

    float sq = e * e;
#pragma unroll
    for (int m = 1; m < 64; m <<= 1) sq += __shfl_xor(sq, m);
    if ((d & 63) == 0) wsum[d >> 6] = sq;
    __syncthreads();
    if (d == 0) s[k] = (wsum[0] + wsum[1]) + (wsum[2] + wsum[3]);
}

// ---------------------------------------------------------------------------
// Distance+argmin as bf16 MFMA GEMM (m97-style 128x128 tile, BK=64).
// score(r,k) = s[k] - 2*(zh·eh + zl·eh + zh·el)   (lo*lo dropped: ~1e-6 err)
// 3 passes x 4 K-steps, all accumulating into the same acc[4][4] (f32x4).
// LDS read swizzle: 16B-chunk index  sub ^ (row&7)  (rows are 128B -> would
// be a 16-way conflict unswizzled); global_load_lds writes linearly, so the
// GLOBAL source is pre-swizzled with the same involution (m173 pattern).
// Epilogue: per-row packed (score_bits<<32 | k) min, shuffle-reduced over the
// 16 lanes of each row group, then u64 atomicMin into packed[] (ties -> min k,
// matching np.argmin first-index semantics).
// ---------------------------------------------------------------------------
__global__ __launch_bounds__(256) void argmin_kernel(
    const unsigned short* __restrict__ zhi, const unsigned short* __restrict__ zlo,
    const unsigned short* __restrict__ ehi, const unsigned short* __restrict__ elo,
    const float* __restrict__ s, unsigned long long* __restrict__ packed)
{
    __shared__ alignas(16) unsigned short As[128 * 64];
    __shared__ alignas(16) unsigned short Bs[128 * 64];
    __shared__ float Ss[128];

    const int tid  = threadIdx.x;
    const int lane = tid & 63;
    const int wid  = tid >> 6;
    const int wm   = wid >> 1;      // wave row  (0..1) -> rows wm*64..+63
    const int wn   = wid & 1;       // wave col  (0..1) -> cols wn*64..+63
    const int lcol = lane & 15;
    const int rhi  = lane >> 4;     // 0..3

    const int bm = blockIdx.x >> 7;
    const int bn = blockIdx.x & 127;
    const size_t r0 = (size_t)bm * 128;
    const int    n0 = bn * 128;

    if (tid < 128) Ss[tid] = s[n0 + tid];

    f32x4 acc[4][4];
    const f32x4 zero = {0.f, 0.f, 0.f, 0.f};
#pragma unroll
    for (int mi = 0; mi < 4; ++mi)
#pragma unroll
        for (int ni = 0; ni < 4; ++ni) acc[mi][ni] = zero;

    const unsigned short* Ap[3] = {zhi, zlo, zhi};
    const unsigned short* Bp[3] = {ehi, ehi, elo};

    for (int p = 0; p < 3; ++p) {
        const char* Ab = (const char*)Ap[p] + r0 * (D * 2);
        const char* Bb = (const char*)Bp[p] + (size_t)n0 * (D * 2);
        for (int kt2 = 0; kt2 < 512; kt2 += 128) {   // byte offset of 64-col K-chunk
            __syncthreads();                          // LDS reuse fence
#pragma unroll
            for (int i = 0; i < 4; ++i) {
                const int c   = i * 256 + tid;        // 16B chunk 0..1023
                const int row = c >> 3;
                const int gs  = (c & 7) ^ (row & 7);  // inverse (= same) swizzle
                gload_lds16(Ab + (size_t)row * 512 + kt2 + gs * 16, (void*)(As + c * 8));
                gload_lds16(Bb + (size_t)row * 512 + kt2 + gs * 16, (void*)(Bs + c * 8));
            }
            __syncthreads();                          // compiler drains vmcnt here

            short8 af[4][2], bfr[4][2];
#pragma unroll
            for (int mi = 0; mi < 4; ++mi) {
                const int rr = wm * 64 + mi * 16 + lcol;
#pragma unroll
                for (int g = 0; g < 2; ++g) {
                    const int sub = 4 * g + rhi;
                    af[mi][g] = *(const short8*)(As + rr * 64 + ((sub ^ (rr & 7)) * 8));
                }
            }
#pragma unroll
            for (int ni = 0; ni < 4; ++ni) {
                const int rr = wn * 64 + ni * 16 + lcol;
#pragma unroll
                for (int g = 0; g < 2; ++g) {
                    const int sub = 4 * g + rhi;
                    bfr[ni][g] = *(const short8*)(Bs + rr * 64 + ((sub ^ (rr & 7)) * 8));
                }
            }
#pragma unroll
            for (int g = 0; g < 2; ++g)
#pragma unroll
                for (int mi = 0; mi < 4; ++mi)
#pragma unroll
                    for (int ni = 0; ni < 4; ++ni)
                        acc[mi][ni] = __builtin_amdgcn_mfma_f32_16x16x32_bf16(
                            af[mi][g], bfr[ni][g], acc[mi][ni], 0, 0, 0);
        }
    }

    // epilogue: C row = (lane>>4)*4 + reg, col = lane&15  [m89-verified layout]
#pragma unroll
    for (int mi = 0; mi < 4; ++mi) {
#pragma unroll
        for (int j = 0; j < 4; ++j) {
            float bv = 3.4e38f;
            int   bk = 0;
#pragma unroll
            for (int ni = 0; ni < 4; ++ni) {
                const float sc = fmaf(-2.f, acc[mi][ni][j], Ss[wn * 64 + ni * 16 + lcol]);
                const int   kk = n0 + wn * 64 + ni * 16 + lcol;
                if (sc < bv) { bv = sc; bk = kk; }    // ni ascending: ties keep low k
            }
            unsigned sb = __float_as_uint(bv);
            sb = (sb & 0x80000000u) ? ~sb : (sb | 0x80000000u);   // monotonic map
            unsigned long long pk = ((unsigned long long)sb << 32) | (unsigned)bk;
#pragma unroll
            for (int m = 1; m < 16; m <<= 1) {
                const unsigned long long o = __shfl_xor(pk, m);
                pk = (o < pk) ? o : pk;
            }
            if (lcol == 0) {
                const size_t rowg = r0 + wm * 64 + mi * 16 + rhi * 4 + j;
                atomicMin(&packed[rowg], pk);
            }
        }
    }
}

// ---------------------------------------------------------------------------
// Gather quantized rows + emit indices as float.
// ---------------------------------------------------------------------------
__global__ __launch_bounds__(256) void gather_kernel(
    const float* __restrict__ emb, const unsigned long long* __restrict__ packed,
    float* __restrict__ outq, float* __restrict__ outidx)
{
    const int row = blockIdx.x;
    const int d   = threadIdx.x;
    const unsigned k = (unsigned)(packed[row] & 0xffffffffULL);
    outq[(size_t)row * D + d] = emb[(size_t)k * D + d];
    if (d == 0) outidx[row] = (float)k;
}

extern "C" void kernel_launch(void* const* d_in, const int* in_sizes, int n_in,
                              void* d_out, int out_size, void* d_ws, size_t ws_size,
                              hipStream_t stream)
{
    const float* z  = (const float*)d_in[0];
    const float* ew = (const float*)d_in[1];
    const float* pw = (const float*)d_in[2];
    const float* pb = (const float*)d_in[3];

    float* out     = (float*)d_out;
    float* out_z   = out;                                  // (B,N,D)
    float* out_emb = out + (size_t)BNROWS * D;             // (K,D)
    float* out_q   = out + 2 * (size_t)BNROWS * D;         // (B,N,D)
    float* out_idx = out + 3 * (size_t)BNROWS * D;         // (B,N) as float

    // ws layout (all 16B aligned):
    unsigned long long* packed = (unsigned long long*)d_ws;               // 128 KB
    float*          sbuf = (float*)((char*)d_ws + 131072);                // 64 KB
    unsigned short* zhi  = (unsigned short*)((char*)d_ws + 196608);       // 8 MB
    unsigned short* zlo  = (unsigned short*)((char*)d_ws + 196608 + 8388608);
    // e-planes live in the out_q region (exactly 16 MB), overwritten by gather
    unsigned short* ehi  = (unsigned short*)out_q;
    unsigned short* elo  = (unsigned short*)out_q + (size_t)KCB * D;

    // init packed argmin buffer to u64-max
    hipMemsetAsync(packed, 0xFF, (size_t)BNROWS * 8, stream);

    // output 0: z passthrough
    hipMemcpyAsync(out_z, z, (size_t)BNROWS * D * sizeof(float),
                   hipMemcpyDeviceToDevice, stream);

    zsplit_kernel<<<(BNROWS * D) / (256 * 4), 256, 0, stream>>>(z, zhi, zlo);
    proj_kernel<<<KCB, 256, 0, stream>>>(ew, pw, pb, out_emb, sbuf, ehi, elo);
    argmin_kernel<<<(BNROWS / 128) * (KCB / 128), 256, 0, stream>>>(
        zhi, zlo, ehi, elo, sbuf, packed);
    gather_kernel<<<BNROWS, 256, 0, stream>>>(out_emb, packed, out_q, out_idx);
}

// Round 3
// 840.936 us; speedup vs baseline: 3.5389x; 1.4664x over previous
//
#include <hip/hip_runtime.h>
#include <hip/hip_bf16.h>

#define D      256
#define KCB    16384
#define BNROWS 16384

typedef __attribute__((ext_vector_type(8))) short short8;   // 8 bf16 = 4 VGPR
typedef __attribute__((ext_vector_type(4))) float f32x4;

__device__ __forceinline__ void gload_lds16(const void* g, void* l) {
    __builtin_amdgcn_global_load_lds(
        (const __attribute__((address_space(1))) void*)g,
        (__attribute__((address_space(3))) void*)l, 16, 0, 0);
}

__device__ __forceinline__ void bf16split(float x, unsigned short& hi, unsigned short& lo) {
    __hip_bfloat16 h = __float2bfloat16(x);
    float hf = __bfloat162float(h);
    __hip_bfloat16 l = __float2bfloat16(x - hf);
    hi = *(unsigned short*)&h;
    lo = *(unsigned short*)&l;
}

// ---------------------------------------------------------------------------
// z -> (z_hi, z_lo) bf16 planes.
// ---------------------------------------------------------------------------
__global__ __launch_bounds__(256) void zsplit_kernel(
    const float* __restrict__ z,
    unsigned short* __restrict__ zhi, unsigned short* __restrict__ zlo)
{
    const int i = blockIdx.x * 256 + threadIdx.x;
    float4 v = ((const float4*)z)[i];
    ushort4 h, l;
    bf16split(v.x, h.x, l.x);
    bf16split(v.y, h.y, l.y);
    bf16split(v.z, h.z, l.z);
    bf16split(v.w, h.w, l.w);
    ((ushort4*)zhi)[i] = h;
    ((ushort4*)zlo)[i] = l;
}

// ---------------------------------------------------------------------------
// proj v2: emb = ew @ pw^T + pb as a tiled fp32 GEMM.
// 64x64 output tile, K=256 in 4 steps of 64. LDS stride 65 (bank-conflict pad).
// L2 traffic: ~80 MB total (vs 4 GB for one-block-per-row).
// ---------------------------------------------------------------------------
__global__ __launch_bounds__(256) void proj_kernel(
    const float* __restrict__ ew, const float* __restrict__ pw,
    const float* __restrict__ pb, float* __restrict__ emb)
{
    __shared__ float Et[64][65];
    __shared__ float Pt[64][65];
    const int tid = threadIdx.x;
    const int tc  = tid & 15, tr = tid >> 4;
    const int k0  = (blockIdx.x >> 2) * 64;
    const int d0  = (blockIdx.x & 3) * 64;

    float acc[4][4];
#pragma unroll
    for (int a = 0; a < 4; ++a)
#pragma unroll
        for (int b = 0; b < 4; ++b) acc[a][b] = 0.f;

    for (int j0 = 0; j0 < 256; j0 += 64) {
        __syncthreads();
#pragma unroll
        for (int i = 0; i < 4; ++i) {
            const int c = i * 256 + tid;
            const int r = c >> 4, c4 = (c & 15) * 4;
            float4 v = *(const float4*)(ew + (size_t)(k0 + r) * 256 + j0 + c4);
            Et[r][c4 + 0] = v.x; Et[r][c4 + 1] = v.y;
            Et[r][c4 + 2] = v.z; Et[r][c4 + 3] = v.w;
            float4 w = *(const float4*)(pw + (size_t)(d0 + r) * 256 + j0 + c4);
            Pt[r][c4 + 0] = w.x; Pt[r][c4 + 1] = w.y;
            Pt[r][c4 + 2] = w.z; Pt[r][c4 + 3] = w.w;
        }
        __syncthreads();
        for (int j = 0; j < 64; ++j) {
            float ev[4], pv[4];
#pragma unroll
            for (int a = 0; a < 4; ++a) ev[a] = Et[tr * 4 + a][j];
#pragma unroll
            for (int b = 0; b < 4; ++b) pv[b] = Pt[tc * 4 + b][j];
#pragma unroll
            for (int a = 0; a < 4; ++a)
#pragma unroll
                for (int b = 0; b < 4; ++b)
                    acc[a][b] = fmaf(ev[a], pv[b], acc[a][b]);
        }
    }

    const float4 bias = *(const float4*)(pb + d0 + tc * 4);
#pragma unroll
    for (int a = 0; a < 4; ++a) {
        float4 o;
        o.x = acc[a][0] + bias.x; o.y = acc[a][1] + bias.y;
        o.z = acc[a][2] + bias.z; o.w = acc[a][3] + bias.w;
        *(float4*)(emb + (size_t)(k0 + tr * 4 + a) * 256 + d0 + tc * 4) = o;
    }
}

// ---------------------------------------------------------------------------
// snorm: s[k] = ||emb[k]||^2  +  bf16 hi/lo planes of emb. Streaming, coalesced.
// Thread owns quarter-row, elements interleaved 16-apart for 64B coalescing.
// ---------------------------------------------------------------------------
__global__ __launch_bounds__(256) void snorm_kernel(
    const float* __restrict__ emb, float* __restrict__ s,
    unsigned short* __restrict__ ehi, unsigned short* __restrict__ elo)
{
    const int tid = threadIdx.x;
    const int row = blockIdx.x * 64 + (tid >> 2);
    const int qd  = tid & 3;
    const size_t base = (size_t)row * 256;
    float sq = 0.f;
#pragma unroll
    for (int j = 0; j < 16; ++j) {
        const int off = qd * 4 + j * 16;
        float4 v = *(const float4*)(emb + base + off);
        ushort4 h, l;
        bf16split(v.x, h.x, l.x);
        bf16split(v.y, h.y, l.y);
        bf16split(v.z, h.z, l.z);
        bf16split(v.w, h.w, l.w);
        *(ushort4*)(ehi + base + off) = h;
        *(ushort4*)(elo + base + off) = l;
        sq = fmaf(v.x, v.x, fmaf(v.y, v.y, fmaf(v.z, v.z, fmaf(v.w, v.w, sq))));
    }
    sq += __shfl_xor(sq, 1);
    sq += __shfl_xor(sq, 2);
    if (qd == 0) s[row] = sq;
}

// ---------------------------------------------------------------------------
// argmin v3: 256x256 tile, 8 waves (2Mx4N), BK=64, 8-phase-style schedule.
// K=768 total = 12 BK-tiles (3 passes {zh*eh, zl*eh, zh*el} x 4).
// Per tile: 4 phases, each {ds_read subtile | stage 1 quarter of t+1 ->
//   raw s_barrier -> 16 MFMA in setprio(1) -> raw s_barrier}.
// Counted vmcnt(2) once per tile at phase 0 (never drain mid-loop).
// LDS: A,B double-buffered 4x32KB = 128KB; swizzle: 16B-chunk slot
//   sub ^ (row&7), global source pre-swizzled (involution) -> 0 conflicts.
// Epilogue: packed (score|k) u64 atomicMin, np.argmin tie semantics.
// ---------------------------------------------------------------------------
__global__ __launch_bounds__(512, 2) void argmin_kernel(
    const unsigned short* __restrict__ zhi, const unsigned short* __restrict__ zlo,
    const unsigned short* __restrict__ ehi, const unsigned short* __restrict__ elo,
    const float* __restrict__ s, unsigned long long* __restrict__ packed)
{
    __shared__ alignas(16) unsigned short Al[2][256 * 64];
    __shared__ alignas(16) unsigned short Bl[2][256 * 64];
    __shared__ float Ss[256];

    const int tid  = threadIdx.x;
    const int lane = tid & 63;
    const int wid  = tid >> 6;
    const int wm   = wid >> 2;      // 0..1: rows wm*128..+127
    const int wn   = wid & 3;       // 0..3: cols wn*64..+63
    const int lcol = lane & 15;
    const int rhi  = lane >> 4;

    const int bm = blockIdx.x >> 6;
    const int bn = blockIdx.x & 63;
    const size_t r0 = (size_t)bm * 256;
    const size_t n0 = (size_t)bn * 256;

    if (tid < 256) Ss[tid] = s[n0 + tid];

    // prologue: stage tile 0 (pass 0: zh, eh; kco = 0)
    {
        const char* A0 = (const char*)zhi + r0 * 512;
        const char* B0 = (const char*)ehi + n0 * 512;
#pragma unroll
        for (int q = 0; q < 4; ++q) {
            const char* src     = (q < 2) ? A0 : B0;
            unsigned short* dst = (q < 2) ? Al[0] : Bl[0];
            const int half = q & 1;
#pragma unroll
            for (int i = 0; i < 2; ++i) {
                const int c  = wid * 128 + i * 64 + lane;
                const int rl = c >> 3, sub = c & 7;
                const int rg = half * 128 + rl;
                gload_lds16(src + (size_t)rg * 512 + ((sub ^ (rg & 7)) << 4),
                            (void*)(dst + half * 8192 + c * 8));
            }
        }
    }
    __syncthreads();   // tile 0 + Ss visible to all waves

    f32x4 acc[8][4];
    const f32x4 zero = {0.f, 0.f, 0.f, 0.f};
#pragma unroll
    for (int m = 0; m < 8; ++m)
#pragma unroll
        for (int n = 0; n < 4; ++n) acc[m][n] = zero;

    short8 afA[4][2], afB[4][2], bfr[2][2];

    for (int t = 0; t < 12; ++t) {
        unsigned short* Ac = Al[t & 1];
        unsigned short* Bc = Bl[t & 1];
        unsigned short* An = Al[(t + 1) & 1];
        unsigned short* Bn = Bl[(t + 1) & 1];
        const int  tn  = t + 1;
        const int  pn  = tn >> 2;
        const bool pre = (tn < 12);
        const char* Ags = ((pn == 1) ? (const char*)zlo : (const char*)zhi)
                          + r0 * 512 + (size_t)(tn & 3) * 128;
        const char* Bgs = ((pn == 2) ? (const char*)elo : (const char*)ehi)
                          + n0 * 512 + (size_t)(tn & 3) * 128;

        // ---------------- phase 0: stage A-half0(t+1); MFMA m0-3 x n0-1 ----
        if (pre) {
#pragma unroll
            for (int i = 0; i < 2; ++i) {
                const int c  = wid * 128 + i * 64 + lane;
                const int rl = c >> 3, sub = c & 7;
                gload_lds16(Ags + (size_t)rl * 512 + ((sub ^ (rl & 7)) << 4),
                            (void*)(An + c * 8));
            }
            asm volatile("s_waitcnt vmcnt(2)" ::: "memory");   // tile t landed
        } else {
            asm volatile("s_waitcnt vmcnt(0)" ::: "memory");
        }
        __builtin_amdgcn_s_barrier();   // all waves' tile-t staging visible

#pragma unroll
        for (int m = 0; m < 4; ++m) {
            const int rr = wm * 128 + m * 16 + lcol;
#pragma unroll
            for (int g = 0; g < 2; ++g)
                afA[m][g] = *(const short8*)(Ac + rr * 64 + (((g * 4 + rhi) ^ (rr & 7)) << 3));
        }
#pragma unroll
        for (int n = 0; n < 2; ++n) {
            const int cc = wn * 64 + n * 16 + lcol;
#pragma unroll
            for (int g = 0; g < 2; ++g)
                bfr[n][g] = *(const short8*)(Bc + cc * 64 + (((g * 4 + rhi) ^ (cc & 7)) << 3));
        }
        __builtin_amdgcn_s_setprio(1);
#pragma unroll
        for (int g = 0; g < 2; ++g)
#pragma unroll
            for (int m = 0; m < 4; ++m)
#pragma unroll
                for (int n = 0; n < 2; ++n)
                    acc[m][n] = __builtin_amdgcn_mfma_f32_16x16x32_bf16(
                        afA[m][g], bfr[n][g], acc[m][n], 0, 0, 0);
        __builtin_amdgcn_s_setprio(0);
        __builtin_amdgcn_s_barrier();

        // ---------------- phase 1: stage A-half1(t+1); MFMA m4-7 x n0-1 ----
        if (pre) {
#pragma unroll
            for (int i = 0; i < 2; ++i) {
                const int c  = wid * 128 + i * 64 + lane;
                const int rl = c >> 3, sub = c & 7;
                const int rg = 128 + rl;
                gload_lds16(Ags + (size_t)rg * 512 + ((sub ^ (rg & 7)) << 4),
                            (void*)(An + 8192 + c * 8));
            }
        }
#pragma unroll
        for (int m = 0; m < 4; ++m) {
            const int rr = wm * 128 + 64 + m * 16 + lcol;
#pragma unroll
            for (int g = 0; g < 2; ++g)
                afB[m][g] = *(const short8*)(Ac + rr * 64 + (((g * 4 + rhi) ^ (rr & 7)) << 3));
        }
        __builtin_amdgcn_s_setprio(1);
#pragma unroll
        for (int g = 0; g < 2; ++g)
#pragma unroll
            for (int m = 0; m < 4; ++m)
#pragma unroll
                for (int n = 0; n < 2; ++n)
                    acc[4 + m][n] = __builtin_amdgcn_mfma_f32_16x16x32_bf16(
                        afB[m][g], bfr[n][g], acc[4 + m][n], 0, 0, 0);
        __builtin_amdgcn_s_setprio(0);
        __builtin_amdgcn_s_barrier();

        // ---------------- phase 2: stage B-half0(t+1); MFMA m4-7 x n2-3 ----
        if (pre) {
#pragma unroll
            for (int i = 0; i < 2; ++i) {
                const int c  = wid * 128 + i * 64 + lane;
                const int rl = c >> 3, sub = c & 7;
                gload_lds16(Bgs + (size_t)rl * 512 + ((sub ^ (rl & 7)) << 4),
                            (void*)(Bn + c * 8));
            }
        }
#pragma unroll
        for (int n = 0; n < 2; ++n) {
            const int cc = wn * 64 + (2 + n) * 16 + lcol;
#pragma unroll
            for (int g = 0; g < 2; ++g)
                bfr[n][g] = *(const short8*)(Bc + cc * 64 + (((g * 4 + rhi) ^ (cc & 7)) << 3));
        }
        __builtin_amdgcn_s_setprio(1);
#pragma unroll
        for (int g = 0; g < 2; ++g)
#pragma unroll
            for (int m = 0; m < 4; ++m)
#pragma unroll
                for (int n = 0; n < 2; ++n)
                    acc[4 + m][2 + n] = __builtin_amdgcn_mfma_f32_16x16x32_bf16(
                        afB[m][g], bfr[n][g], acc[4 + m][2 + n], 0, 0, 0);
        __builtin_amdgcn_s_setprio(0);
        __builtin_amdgcn_s_barrier();

        // ---------------- phase 3: stage B-half1(t+1); MFMA m0-3 x n2-3 ----
        if (pre) {
#pragma unroll
            for (int i = 0; i < 2; ++i) {
                const int c  = wid * 128 + i * 64 + lane;
                const int rl = c >> 3, sub = c & 7;
                const int rg = 128 + rl;
                gload_lds16(Bgs + (size_t)rg * 512 + ((sub ^ (rg & 7)) << 4),
                            (void*)(Bn + 8192 + c * 8));
            }
        }
        __builtin_amdgcn_s_setprio(1);
#pragma unroll
        for (int g = 0; g < 2; ++g)
#pragma unroll
            for (int m = 0; m < 4; ++m)
#pragma unroll
                for (int n = 0; n < 2; ++n)
                    acc[m][2 + n] = __builtin_amdgcn_mfma_f32_16x16x32_bf16(
                        afA[m][g], bfr[n][g], acc[m][2 + n], 0, 0, 0);
        __builtin_amdgcn_s_setprio(0);
        __builtin_amdgcn_s_barrier();
    }

    // epilogue: C row=(lane>>4)*4+reg, col=lane&15 per 16x16 fragment
#pragma unroll
    for (int m = 0; m < 8; ++m) {
#pragma unroll
        for (int j = 0; j < 4; ++j) {
            float bv = 3.4e38f;
            int   bk = 0;
#pragma unroll
            for (int n = 0; n < 4; ++n) {
                const float sc = fmaf(-2.f, acc[m][n][j], Ss[wn * 64 + n * 16 + lcol]);
                const int   kk = (int)n0 + wn * 64 + n * 16 + lcol;
                if (sc < bv) { bv = sc; bk = kk; }
            }
            unsigned sb = __float_as_uint(bv);
            sb = (sb & 0x80000000u) ? ~sb : (sb | 0x80000000u);
            unsigned long long pk = ((unsigned long long)sb << 32) | (unsigned)bk;
#pragma unroll
            for (int mm = 1; mm < 16; mm <<= 1) {
                const unsigned long long o = __shfl_xor(pk, mm);
                pk = (o < pk) ? o : pk;
            }
            if (lcol == 0) {
                const size_t rowg = r0 + wm * 128 + m * 16 + rhi * 4 + j;
                atomicMin(&packed[rowg], pk);
            }
        }
    }
}

// ---------------------------------------------------------------------------
// Gather quantized rows + emit indices as float.
// ---------------------------------------------------------------------------
__global__ __launch_bounds__(256) void gather_kernel(
    const float* __restrict__ emb, const unsigned long long* __restrict__ packed,
    float* __restrict__ outq, float* __restrict__ outidx)
{
    const int row = blockIdx.x;
    const int d   = threadIdx.x;
    const unsigned k = (unsigned)(packed[row] & 0xffffffffULL);
    outq[(size_t)row * D + d] = emb[(size_t)k * D + d];
    if (d == 0) outidx[row] = (float)k;
}

extern "C" void kernel_launch(void* const* d_in, const int* in_sizes, int n_in,
                              void* d_out, int out_size, void* d_ws, size_t ws_size,
                              hipStream_t stream)
{
    const float* z  = (const float*)d_in[0];
    const float* ew = (const float*)d_in[1];
    const float* pw = (const float*)d_in[2];
    const float* pb = (const float*)d_in[3];

    float* out     = (float*)d_out;
    float* out_z   = out;                                  // (B,N,D)
    float* out_emb = out + (size_t)BNROWS * D;             // (K,D)
    float* out_q   = out + 2 * (size_t)BNROWS * D;         // (B,N,D)
    float* out_idx = out + 3 * (size_t)BNROWS * D;         // (B,N) as float

    unsigned long long* packed = (unsigned long long*)d_ws;               // 128 KB
    float*          sbuf = (float*)((char*)d_ws + 131072);                // 64 KB
    unsigned short* zhi  = (unsigned short*)((char*)d_ws + 196608);       // 8 MB
    unsigned short* zlo  = (unsigned short*)((char*)d_ws + 196608 + 8388608);
    // e-planes live in the out_q region (exactly 16 MB), overwritten by gather
    unsigned short* ehi  = (unsigned short*)out_q;
    unsigned short* elo  = (unsigned short*)out_q + (size_t)KCB * D;

    hipMemsetAsync(packed, 0xFF, (size_t)BNROWS * 8, stream);

    hipMemcpyAsync(out_z, z, (size_t)BNROWS * D * sizeof(float),
                   hipMemcpyDeviceToDevice, stream);

    zsplit_kernel<<<(BNROWS * D) / (256 * 4), 256, 0, stream>>>(z, zhi, zlo);
    proj_kernel<<<(KCB / 64) * 4, 256, 0, stream>>>(ew, pw, pb, out_emb);
    snorm_kernel<<<KCB / 64, 256, 0, stream>>>(out_emb, sbuf, ehi, elo);
    argmin_kernel<<<(BNROWS / 256) * (KCB / 256), 512, 0, stream>>>(
        zhi, zlo, ehi, elo, sbuf, packed);
    gather_kernel<<<BNROWS, 256, 0, stream>>>(out_emb, packed, out_q, out_idx);
}

// Round 4
// 627.202 us; speedup vs baseline: 4.7448x; 1.3408x over previous
//
#include <hip/hip_runtime.h>
#include <hip/hip_bf16.h>

#define D      256
#define KCB    16384
#define BNROWS 16384

typedef __attribute__((ext_vector_type(8))) short short8;   // 8 bf16 = 4 VGPR
typedef __attribute__((ext_vector_type(4))) float f32x4;
typedef unsigned long long u64;

__device__ __forceinline__ void gload_lds16(const void* g, void* l) {
    __builtin_amdgcn_global_load_lds(
        (const __attribute__((address_space(1))) void*)g,
        (__attribute__((address_space(3))) void*)l, 16, 0, 0);
}

__device__ __forceinline__ void bf16split(float x, unsigned short& hi, unsigned short& lo) {
    __hip_bfloat16 h = __float2bfloat16(x);
    float hf = __bfloat162float(h);
    __hip_bfloat16 l = __float2bfloat16(x - hf);
    hi = *(unsigned short*)&h;
    lo = *(unsigned short*)&l;
}

// ---------------------------------------------------------------------------
// z -> (z_hi, z_lo) bf16 planes.
// ---------------------------------------------------------------------------
__global__ __launch_bounds__(256) void zsplit_kernel(
    const float* __restrict__ z,
    unsigned short* __restrict__ zhi, unsigned short* __restrict__ zlo)
{
    const int i = blockIdx.x * 256 + threadIdx.x;
    float4 v = ((const float4*)z)[i];
    ushort4 h, l;
    bf16split(v.x, h.x, l.x);
    bf16split(v.y, h.y, l.y);
    bf16split(v.z, h.z, l.z);
    bf16split(v.w, h.w, l.w);
    ((ushort4*)zhi)[i] = h;
    ((ushort4*)zlo)[i] = l;
}

// ---------------------------------------------------------------------------
// proj: emb = ew @ pw^T + pb as a tiled fp32 GEMM (64x64 tile, LDS pad 65).
// ---------------------------------------------------------------------------
__global__ __launch_bounds__(256) void proj_kernel(
    const float* __restrict__ ew, const float* __restrict__ pw,
    const float* __restrict__ pb, float* __restrict__ emb)
{
    __shared__ float Et[64][65];
    __shared__ float Pt[64][65];
    const int tid = threadIdx.x;
    const int tc  = tid & 15, tr = tid >> 4;
    const int k0  = (blockIdx.x >> 2) * 64;
    const int d0  = (blockIdx.x & 3) * 64;

    float acc[4][4];
#pragma unroll
    for (int a = 0; a < 4; ++a)
#pragma unroll
        for (int b = 0; b < 4; ++b) acc[a][b] = 0.f;

    for (int j0 = 0; j0 < 256; j0 += 64) {
        __syncthreads();
#pragma unroll
        for (int i = 0; i < 4; ++i) {
            const int c = i * 256 + tid;
            const int r = c >> 4, c4 = (c & 15) * 4;
            float4 v = *(const float4*)(ew + (size_t)(k0 + r) * 256 + j0 + c4);
            Et[r][c4 + 0] = v.x; Et[r][c4 + 1] = v.y;
            Et[r][c4 + 2] = v.z; Et[r][c4 + 3] = v.w;
            float4 w = *(const float4*)(pw + (size_t)(d0 + r) * 256 + j0 + c4);
            Pt[r][c4 + 0] = w.x; Pt[r][c4 + 1] = w.y;
            Pt[r][c4 + 2] = w.z; Pt[r][c4 + 3] = w.w;
        }
        __syncthreads();
        for (int j = 0; j < 64; ++j) {
            float ev[4], pv[4];
#pragma unroll
            for (int a = 0; a < 4; ++a) ev[a] = Et[tr * 4 + a][j];
#pragma unroll
            for (int b = 0; b < 4; ++b) pv[b] = Pt[tc * 4 + b][j];
#pragma unroll
            for (int a = 0; a < 4; ++a)
#pragma unroll
                for (int b = 0; b < 4; ++b)
                    acc[a][b] = fmaf(ev[a], pv[b], acc[a][b]);
        }
    }

    const float4 bias = *(const float4*)(pb + d0 + tc * 4);
#pragma unroll
    for (int a = 0; a < 4; ++a) {
        float4 o;
        o.x = acc[a][0] + bias.x; o.y = acc[a][1] + bias.y;
        o.z = acc[a][2] + bias.z; o.w = acc[a][3] + bias.w;
        *(float4*)(emb + (size_t)(k0 + tr * 4 + a) * 256 + d0 + tc * 4) = o;
    }
}

// ---------------------------------------------------------------------------
// snorm: s[k] = ||emb[k]||^2 + bf16 hi/lo planes of emb.
// ---------------------------------------------------------------------------
__global__ __launch_bounds__(256) void snorm_kernel(
    const float* __restrict__ emb, float* __restrict__ s,
    unsigned short* __restrict__ ehi, unsigned short* __restrict__ elo)
{
    const int tid = threadIdx.x;
    const int row = blockIdx.x * 64 + (tid >> 2);
    const int qd  = tid & 3;
    const size_t base = (size_t)row * 256;
    float sq = 0.f;
#pragma unroll
    for (int j = 0; j < 16; ++j) {
        const int off = qd * 4 + j * 16;
        float4 v = *(const float4*)(emb + base + off);
        ushort4 h, l;
        bf16split(v.x, h.x, l.x);
        bf16split(v.y, h.y, l.y);
        bf16split(v.z, h.z, l.z);
        bf16split(v.w, h.w, l.w);
        *(ushort4*)(ehi + base + off) = h;
        *(ushort4*)(elo + base + off) = l;
        sq = fmaf(v.x, v.x, fmaf(v.y, v.y, fmaf(v.z, v.z, fmaf(v.w, v.w, sq))));
    }
    sq += __shfl_xor(sq, 1);
    sq += __shfl_xor(sq, 2);
    if (qd == 0) s[row] = sq;
}

// ---------------------------------------------------------------------------
// argmin v4: 256x256 tile, 8 waves (2Mx4N), BK=64, 4-phase/tile schedule.
// Changes vs v3:
//  * NO global atomics: block-local LDS combine -> plain store to
//    partial[row][64] (one u64 per (row, bn)); separate reduce kernel.
//  * All of tile t+1's A staged at phase 0, B at phase 1 -> >=2.5-phase
//    latency slack; single counted vmcnt(4) per tile at phase 0.
//  * XCD-aware block swizzle (4096 blocks % 8 == 0, bijective).
// ---------------------------------------------------------------------------
__global__ __launch_bounds__(512) void argmin_kernel(
    const unsigned short* __restrict__ zhi, const unsigned short* __restrict__ zlo,
    const unsigned short* __restrict__ ehi, const unsigned short* __restrict__ elo,
    const float* __restrict__ s, u64* __restrict__ partial)
{
    __shared__ alignas(16) unsigned short Al[2][256 * 64];
    __shared__ alignas(16) unsigned short Bl[2][256 * 64];
    __shared__ float Ss[256];

    const int tid  = threadIdx.x;
    const int lane = tid & 63;
    const int wid  = tid >> 6;
    const int wm   = wid >> 2;      // 0..1: rows wm*128..+127
    const int wn   = wid & 3;       // 0..3: cols wn*64..+63
    const int lcol = lane & 15;
    const int rhi  = lane >> 4;

    // XCD swizzle: same-XCD blocks get a contiguous chunk of the bm-major grid
    const int bid = blockIdx.x;
    const int lin = (bid & 7) * 512 + (bid >> 3);
    const int bm  = lin >> 6;
    const int bn  = lin & 63;
    const size_t r0 = (size_t)bm * 256;
    const size_t n0 = (size_t)bn * 256;

    if (tid < 256) Ss[tid] = s[n0 + tid];

    // stage one quarter-pair (both halves of A or B) of tile t into dst
    // global source pre-swizzled with the (sub ^ (row&7)) involution so the
    // linear gload_lds dest + swizzled ds_read are conflict-free.
#define STAGE_AB(srcbase, dst)                                                \
    {                                                                         \
        _Pragma("unroll")                                                     \
        for (int h = 0; h < 2; ++h) {                                         \
            _Pragma("unroll")                                                 \
            for (int i = 0; i < 2; ++i) {                                     \
                const int c  = wid * 128 + i * 64 + lane;                     \
                const int rl = c >> 3, sub = c & 7;                           \
                const int rg = h * 128 + rl;                                  \
                gload_lds16((srcbase) + (size_t)rg * 512 + ((sub ^ (rg & 7)) << 4), \
                            (void*)((dst) + h * 8192 + c * 8));               \
            }                                                                 \
        }                                                                     \
    }

    // prologue: stage tile 0 (plane 0: zh, eh)
    {
        const char* A0 = (const char*)zhi + r0 * 512;
        const char* B0 = (const char*)ehi + n0 * 512;
        STAGE_AB(A0, Al[0]);
        STAGE_AB(B0, Bl[0]);
    }
    asm volatile("s_waitcnt lgkmcnt(0)" ::: "memory");   // Ss ds_write drained

    f32x4 acc[8][4];
    const f32x4 zero = {0.f, 0.f, 0.f, 0.f};
#pragma unroll
    for (int m = 0; m < 8; ++m)
#pragma unroll
        for (int n = 0; n < 4; ++n) acc[m][n] = zero;

    short8 afA[4][2], afB[4][2], bfr[2][2];

    for (int t = 0; t < 12; ++t) {
        unsigned short* Ac = Al[t & 1];
        unsigned short* Bc = Bl[t & 1];
        unsigned short* An = Al[(t + 1) & 1];
        unsigned short* Bn = Bl[(t + 1) & 1];
        const int  tn  = t + 1;
        const int  pn  = tn >> 2;
        const bool pre = (tn < 12);
        const char* Ags = ((pn == 1) ? (const char*)zlo : (const char*)zhi)
                          + r0 * 512 + (size_t)(tn & 3) * 128;
        const char* Bgs = ((pn == 2) ? (const char*)elo : (const char*)ehi)
                          + n0 * 512 + (size_t)(tn & 3) * 128;

        // ---- phase 0: stage ALL of A(t+1); vmcnt(4); MFMA m0-3 x n0-1 ----
        if (pre) {
            STAGE_AB(Ags, An);
            asm volatile("s_waitcnt vmcnt(4)" ::: "memory");  // tile t resident
        } else {
            asm volatile("s_waitcnt vmcnt(0)" ::: "memory");
        }
        __builtin_amdgcn_s_barrier();

#pragma unroll
        for (int m = 0; m < 4; ++m) {
            const int rr = wm * 128 + m * 16 + lcol;
#pragma unroll
            for (int g = 0; g < 2; ++g)
                afA[m][g] = *(const short8*)(Ac + rr * 64 + (((g * 4 + rhi) ^ (rr & 7)) << 3));
        }
#pragma unroll
        for (int n = 0; n < 2; ++n) {
            const int cc = wn * 64 + n * 16 + lcol;
#pragma unroll
            for (int g = 0; g < 2; ++g)
                bfr[n][g] = *(const short8*)(Bc + cc * 64 + (((g * 4 + rhi) ^ (cc & 7)) << 3));
        }
        __builtin_amdgcn_s_setprio(1);
#pragma unroll
        for (int g = 0; g < 2; ++g)
#pragma unroll
            for (int m = 0; m < 4; ++m)
#pragma unroll
                for (int n = 0; n < 2; ++n)
                    acc[m][n] = __builtin_amdgcn_mfma_f32_16x16x32_bf16(
                        afA[m][g], bfr[n][g], acc[m][n], 0, 0, 0);
        __builtin_amdgcn_s_setprio(0);
        __builtin_amdgcn_s_barrier();

        // ---- phase 1: stage ALL of B(t+1); MFMA m4-7 x n0-1 --------------
        if (pre) STAGE_AB(Bgs, Bn);
#pragma unroll
        for (int m = 0; m < 4; ++m) {
            const int rr = wm * 128 + 64 + m * 16 + lcol;
#pragma unroll
            for (int g = 0; g < 2; ++g)
                afB[m][g] = *(const short8*)(Ac + rr * 64 + (((g * 4 + rhi) ^ (rr & 7)) << 3));
        }
        __builtin_amdgcn_s_setprio(1);
#pragma unroll
        for (int g = 0; g < 2; ++g)
#pragma unroll
            for (int m = 0; m < 4; ++m)
#pragma unroll
                for (int n = 0; n < 2; ++n)
                    acc[4 + m][n] = __builtin_amdgcn_mfma_f32_16x16x32_bf16(
                        afB[m][g], bfr[n][g], acc[4 + m][n], 0, 0, 0);
        __builtin_amdgcn_s_setprio(0);
        __builtin_amdgcn_s_barrier();

        // ---- phase 2: MFMA m4-7 x n2-3 -----------------------------------
#pragma unroll
        for (int n = 0; n < 2; ++n) {
            const int cc = wn * 64 + (2 + n) * 16 + lcol;
#pragma unroll
            for (int g = 0; g < 2; ++g)
                bfr[n][g] = *(const short8*)(Bc + cc * 64 + (((g * 4 + rhi) ^ (cc & 7)) << 3));
        }
        __builtin_amdgcn_s_setprio(1);
#pragma unroll
        for (int g = 0; g < 2; ++g)
#pragma unroll
            for (int m = 0; m < 4; ++m)
#pragma unroll
                for (int n = 0; n < 2; ++n)
                    acc[4 + m][2 + n] = __builtin_amdgcn_mfma_f32_16x16x32_bf16(
                        afB[m][g], bfr[n][g], acc[4 + m][2 + n], 0, 0, 0);
        __builtin_amdgcn_s_setprio(0);
        __builtin_amdgcn_s_barrier();

        // ---- phase 3: MFMA m0-3 x n2-3 -----------------------------------
        __builtin_amdgcn_s_setprio(1);
#pragma unroll
        for (int g = 0; g < 2; ++g)
#pragma unroll
            for (int m = 0; m < 4; ++m)
#pragma unroll
                for (int n = 0; n < 2; ++n)
                    acc[m][2 + n] = __builtin_amdgcn_mfma_f32_16x16x32_bf16(
                        afA[m][g], bfr[n][g], acc[m][2 + n], 0, 0, 0);
        __builtin_amdgcn_s_setprio(0);
        __builtin_amdgcn_s_barrier();
    }
#undef STAGE_AB

    // ---- epilogue: block-local argmin, no global atomics ------------------
    // cand[256][4] u64 overlays Al (loop reads all done: final barrier above)
    u64* cand = (u64*)Al;
#pragma unroll
    for (int m = 0; m < 8; ++m) {
#pragma unroll
        for (int j = 0; j < 4; ++j) {
            float bv = 3.4e38f;
            int   bk = 0;
#pragma unroll
            for (int n = 0; n < 4; ++n) {
                const float sc = fmaf(-2.f, acc[m][n][j], Ss[wn * 64 + n * 16 + lcol]);
                const int   kk = (int)n0 + wn * 64 + n * 16 + lcol;
                if (sc < bv) { bv = sc; bk = kk; }     // ascending: ties keep low k
            }
            unsigned sb = __float_as_uint(bv);
            sb = (sb & 0x80000000u) ? ~sb : (sb | 0x80000000u);  // order-preserving
            u64 pk = ((u64)sb << 32) | (unsigned)bk;
#pragma unroll
            for (int mm = 1; mm < 16; mm <<= 1) {
                const u64 o = __shfl_xor(pk, mm);
                pk = (o < pk) ? o : pk;
            }
            if (lcol == 0)
                cand[(wm * 128 + m * 16 + rhi * 4 + j) * 4 + wn] = pk;
        }
    }
    __syncthreads();
    if (tid < 256) {
        const u64* c4 = cand + (size_t)tid * 4;
        u64 pk = c4[0];
        if (c4[1] < pk) pk = c4[1];
        if (c4[2] < pk) pk = c4[2];
        if (c4[3] < pk) pk = c4[3];
        partial[(r0 + tid) * 64 + bn] = pk;
    }
}

// ---------------------------------------------------------------------------
// reduce: per row, min over the 64 col-block partials -> qidx.
// One wave per row; 64 contiguous u64 = 512B coalesced read.
// ---------------------------------------------------------------------------
__global__ __launch_bounds__(256) void reduce_kernel(
    const u64* __restrict__ partial, int* __restrict__ qidx)
{
    const int row  = blockIdx.x * 4 + (threadIdx.x >> 6);
    const int lane = threadIdx.x & 63;
    u64 pk = partial[(size_t)row * 64 + lane];
#pragma unroll
    for (int m = 1; m < 64; m <<= 1) {
        const u64 o = __shfl_xor(pk, m);
        pk = (o < pk) ? o : pk;
    }
    if (lane == 0) qidx[row] = (int)(pk & 0xffffffffULL);
}

// ---------------------------------------------------------------------------
// Gather quantized rows + emit indices as float.
// ---------------------------------------------------------------------------
__global__ __launch_bounds__(256) void gather_kernel(
    const float* __restrict__ emb, const int* __restrict__ qidx,
    float* __restrict__ outq, float* __restrict__ outidx)
{
    const int row = blockIdx.x;
    const int d   = threadIdx.x;
    const int k   = qidx[row];
    outq[(size_t)row * D + d] = emb[(size_t)k * D + d];
    if (d == 0) outidx[row] = (float)k;
}

extern "C" void kernel_launch(void* const* d_in, const int* in_sizes, int n_in,
                              void* d_out, int out_size, void* d_ws, size_t ws_size,
                              hipStream_t stream)
{
    const float* z  = (const float*)d_in[0];
    const float* ew = (const float*)d_in[1];
    const float* pw = (const float*)d_in[2];
    const float* pb = (const float*)d_in[3];

    float* out     = (float*)d_out;
    float* out_z   = out;                                  // (B,N,D)
    float* out_emb = out + (size_t)BNROWS * D;             // (K,D)
    float* out_q   = out + 2 * (size_t)BNROWS * D;         // (B,N,D)
    float* out_idx = out + 3 * (size_t)BNROWS * D;         // (B,N) as float

    // ws: sbuf 64KB | qidx 64KB | zhi 8MB | zlo 8MB   (~16.1 MB)
    float*          sbuf = (float*)d_ws;
    int*            qidx = (int*)((char*)d_ws + 65536);
    unsigned short* zhi  = (unsigned short*)((char*)d_ws + 131072);
    unsigned short* zlo  = (unsigned short*)((char*)d_ws + 131072 + 8388608);
    // e-planes live in out_q (16 MB), overwritten by gather afterwards
    unsigned short* ehi  = (unsigned short*)out_q;
    unsigned short* elo  = (unsigned short*)out_q + (size_t)KCB * D;
    // partial argmin table (8 MB) lives in out_z, overwritten by the late
    // z-memcpy after reduce_kernel has consumed it
    u64* partial = (u64*)out_z;

    zsplit_kernel<<<(BNROWS * D) / (256 * 4), 256, 0, stream>>>(z, zhi, zlo);
    proj_kernel<<<(KCB / 64) * 4, 256, 0, stream>>>(ew, pw, pb, out_emb);
    snorm_kernel<<<KCB / 64, 256, 0, stream>>>(out_emb, sbuf, ehi, elo);
    argmin_kernel<<<(BNROWS / 256) * (KCB / 256), 512, 0, stream>>>(
        zhi, zlo, ehi, elo, sbuf, partial);
    reduce_kernel<<<BNROWS / 4, 256, 0, stream>>>(partial, qidx);
    // output 0: z passthrough (after partial is consumed)
    hipMemcpyAsync(out_z, z, (size_t)BNROWS * D * sizeof(float),
                   hipMemcpyDeviceToDevice, stream);
    gather_kernel<<<BNROWS, 256, 0, stream>>>(out_emb, qidx, out_q, out_idx);
}

// Round 5
// 531.498 us; speedup vs baseline: 5.5992x; 1.1801x over previous
//
#include <hip/hip_runtime.h>
#include <hip/hip_bf16.h>

#define D      256
#define KCB    16384
#define BNROWS 16384

typedef __attribute__((ext_vector_type(8))) short short8;   // 8 bf16 = 4 VGPR
typedef __attribute__((ext_vector_type(4))) float f32x4;
typedef unsigned long long u64;

__device__ __forceinline__ void gload_lds16(const void* g, void* l) {
    __builtin_amdgcn_global_load_lds(
        (const __attribute__((address_space(1))) void*)g,
        (__attribute__((address_space(3))) void*)l, 16, 0, 0);
}

__device__ __forceinline__ void bf16split(float x, unsigned short& hi, unsigned short& lo) {
    __hip_bfloat16 h = __float2bfloat16(x);
    float hf = __bfloat162float(h);
    __hip_bfloat16 l = __float2bfloat16(x - hf);
    hi = *(unsigned short*)&h;
    lo = *(unsigned short*)&l;
}

// ---------------------------------------------------------------------------
// z -> (z_hi, z_lo) bf16 planes.
// ---------------------------------------------------------------------------
__global__ __launch_bounds__(256) void zsplit_kernel(
    const float* __restrict__ z,
    unsigned short* __restrict__ zhi, unsigned short* __restrict__ zlo)
{
    const int i = blockIdx.x * 256 + threadIdx.x;
    float4 v = ((const float4*)z)[i];
    ushort4 h, l;
    bf16split(v.x, h.x, l.x);
    bf16split(v.y, h.y, l.y);
    bf16split(v.z, h.z, l.z);
    bf16split(v.w, h.w, l.w);
    ((ushort4*)zhi)[i] = h;
    ((ushort4*)zlo)[i] = l;
}

// ---------------------------------------------------------------------------
// proj: emb = ew @ pw^T + pb as a tiled fp32 GEMM (64x64 tile, LDS pad 65).
// ---------------------------------------------------------------------------
__global__ __launch_bounds__(256) void proj_kernel(
    const float* __restrict__ ew, const float* __restrict__ pw,
    const float* __restrict__ pb, float* __restrict__ emb)
{
    __shared__ float Et[64][65];
    __shared__ float Pt[64][65];
    const int tid = threadIdx.x;
    const int tc  = tid & 15, tr = tid >> 4;
    const int k0  = (blockIdx.x >> 2) * 64;
    const int d0  = (blockIdx.x & 3) * 64;

    float acc[4][4];
#pragma unroll
    for (int a = 0; a < 4; ++a)
#pragma unroll
        for (int b = 0; b < 4; ++b) acc[a][b] = 0.f;

    for (int j0 = 0; j0 < 256; j0 += 64) {
        __syncthreads();
#pragma unroll
        for (int i = 0; i < 4; ++i) {
            const int c = i * 256 + tid;
            const int r = c >> 4, c4 = (c & 15) * 4;
            float4 v = *(const float4*)(ew + (size_t)(k0 + r) * 256 + j0 + c4);
            Et[r][c4 + 0] = v.x; Et[r][c4 + 1] = v.y;
            Et[r][c4 + 2] = v.z; Et[r][c4 + 3] = v.w;
            float4 w = *(const float4*)(pw + (size_t)(d0 + r) * 256 + j0 + c4);
            Pt[r][c4 + 0] = w.x; Pt[r][c4 + 1] = w.y;
            Pt[r][c4 + 2] = w.z; Pt[r][c4 + 3] = w.w;
        }
        __syncthreads();
        for (int j = 0; j < 64; ++j) {
            float ev[4], pv[4];
#pragma unroll
            for (int a = 0; a < 4; ++a) ev[a] = Et[tr * 4 + a][j];
#pragma unroll
            for (int b = 0; b < 4; ++b) pv[b] = Pt[tc * 4 + b][j];
#pragma unroll
            for (int a = 0; a < 4; ++a)
#pragma unroll
                for (int b = 0; b < 4; ++b)
                    acc[a][b] = fmaf(ev[a], pv[b], acc[a][b]);
        }
    }

    const float4 bias = *(const float4*)(pb + d0 + tc * 4);
#pragma unroll
    for (int a = 0; a < 4; ++a) {
        float4 o;
        o.x = acc[a][0] + bias.x; o.y = acc[a][1] + bias.y;
        o.z = acc[a][2] + bias.z; o.w = acc[a][3] + bias.w;
        *(float4*)(emb + (size_t)(k0 + tr * 4 + a) * 256 + d0 + tc * 4) = o;
    }
}

// ---------------------------------------------------------------------------
// snorm: s[k] = ||emb[k]||^2 + bf16 hi/lo planes of emb.
// ---------------------------------------------------------------------------
__global__ __launch_bounds__(256) void snorm_kernel(
    const float* __restrict__ emb, float* __restrict__ s,
    unsigned short* __restrict__ ehi, unsigned short* __restrict__ elo)
{
    const int tid = threadIdx.x;
    const int row = blockIdx.x * 64 + (tid >> 2);
    const int qd  = tid & 3;
    const size_t base = (size_t)row * 256;
    float sq = 0.f;
#pragma unroll
    for (int j = 0; j < 16; ++j) {
        const int off = qd * 4 + j * 16;
        float4 v = *(const float4*)(emb + base + off);
        ushort4 h, l;
        bf16split(v.x, h.x, l.x);
        bf16split(v.y, h.y, l.y);
        bf16split(v.z, h.z, l.z);
        bf16split(v.w, h.w, l.w);
        *(ushort4*)(ehi + base + off) = h;
        *(ushort4*)(elo + base + off) = l;
        sq = fmaf(v.x, v.x, fmaf(v.y, v.y, fmaf(v.z, v.z, fmaf(v.w, v.w, sq))));
    }
    sq += __shfl_xor(sq, 1);
    sq += __shfl_xor(sq, 2);
    if (qd == 0) s[row] = sq;
}

// ---------------------------------------------------------------------------
// argmin v5: 256x256 tile, 8 waves (2Mx4N), BK=64 split as two K-halves.
// Per tile 4 phases:
//   p0: read A(g0) m0-7 + B(g0) n0-1 | issue Akh0(t+1) | bar | MFMA g0 x n0-1
//   p1: read B(g0) n2-3              | issue Bkh0(t+1) | vmcnt(4) bar | MFMA g0 x n2-3
//   p2: read A(g1) + B(g1) n0-1      | issue Akh1(t+1) | bar | MFMA g1 x n0-1
//   p3: read B(g1) n2-3              | issue Bkh1(t+1) | vmcnt(4) bar | MFMA g1 x n2-3
// ds_reads sit BEFORE the barrier (latency overlaps barrier wait); each
// phase's reads use data forced-resident by the PREVIOUS phase's vmcnt+bar.
// Half = 256 rows x 32 cols; 64-B rows swizzled sub^((row^(row>>2))&3)
// (<=2-way banks = free), pre-applied on the global source (bijective).
// Natural block order (round-3 config: measured 3.3x lower L2-miss traffic
// than the bm-chunk XCD swizzle).
// Epilogue: block-local LDS combine -> partial[row][64]; no global atomics.
// ---------------------------------------------------------------------------
__global__ __launch_bounds__(512) void argmin_kernel(
    const unsigned short* __restrict__ zhi, const unsigned short* __restrict__ zlo,
    const unsigned short* __restrict__ ehi, const unsigned short* __restrict__ elo,
    const float* __restrict__ s, u64* __restrict__ partial)
{
    __shared__ alignas(16) unsigned short Al[2][2][8192];   // [buf][khalf][256*32]
    __shared__ alignas(16) unsigned short Bl[2][2][8192];
    __shared__ float Ss[256];

    const int tid  = threadIdx.x;
    const int lane = tid & 63;
    const int wid  = tid >> 6;
    const int wm   = wid >> 2;      // 0..1: rows wm*128..+127
    const int wn   = wid & 3;       // 0..3: cols wn*64..+63
    const int lcol = lane & 15;
    const int rhi  = lane >> 4;

    const int bm = blockIdx.x >> 6;        // natural order (no XCD swizzle)
    const int bn = blockIdx.x & 63;
    const size_t r0 = (size_t)bm * 256;
    const size_t n0 = (size_t)bn * 256;

    if (tid < 256) Ss[tid] = s[n0 + tid];

    // stage one K-half (256 rows x 32 cols, 2 gloads/wave). LDS dest linear,
    // global source pre-swizzled with the same involution used on reads.
#define ISSUE_HALF(srcb, dstb)                                                \
    {                                                                         \
        _Pragma("unroll")                                                     \
        for (int i = 0; i < 2; ++i) {                                         \
            const int c   = wid * 128 + i * 64 + lane;                        \
            const int row = c >> 2, sub = c & 3;                              \
            const int gs  = sub ^ ((row ^ (row >> 2)) & 3);                   \
            gload_lds16((srcb) + (size_t)row * 512 + (gs << 4),               \
                        (void*)((dstb) + c * 8));                             \
        }                                                                     \
    }

    // fragment read with the matching swizzle
#define AFRAG(buf, g, row) \
    (*(const short8*)(&Al[buf][g][(row) * 32 + ((rhi ^ (((row) ^ ((row) >> 2)) & 3)) << 3)]))
#define BFRAG(buf, g, row) \
    (*(const short8*)(&Bl[buf][g][(row) * 32 + ((rhi ^ (((row) ^ ((row) >> 2)) & 3)) << 3)]))

    // prologue: tile 0 (plane 0: zh, eh), issue order Akh0, Bkh0, Akh1, Bkh1
    {
        const char* A0 = (const char*)zhi + r0 * 512;
        const char* B0 = (const char*)ehi + n0 * 512;
        ISSUE_HALF(A0,      &Al[0][0][0]);
        ISSUE_HALF(B0,      &Bl[0][0][0]);
        ISSUE_HALF(A0 + 64, &Al[0][1][0]);
        ISSUE_HALF(B0 + 64, &Bl[0][1][0]);
    }
    asm volatile("s_waitcnt vmcnt(4) lgkmcnt(0)" ::: "memory");  // kh0 in, Ss in
    __builtin_amdgcn_s_barrier();

    f32x4 acc[8][4];
    const f32x4 zero = {0.f, 0.f, 0.f, 0.f};
#pragma unroll
    for (int m = 0; m < 8; ++m)
#pragma unroll
        for (int n = 0; n < 4; ++n) acc[m][n] = zero;

    for (int t = 0; t < 12; ++t) {
        const int cb = t & 1, nb = cb ^ 1;
        const int tn = t + 1;
        const bool pre = (tn < 12);
        const int pn = tn >> 2;
        const char* Ags = ((pn == 1) ? (const char*)zlo : (const char*)zhi)
                          + r0 * 512 + (size_t)(tn & 3) * 128;
        const char* Bgs = ((pn == 2) ? (const char*)elo : (const char*)ehi)
                          + n0 * 512 + (size_t)(tn & 3) * 128;

        short8 a[8], b0[2], b1[2];

        // ---- phase 0: A(g0), B(g0) n0-1; issue Akh0(t+1) ------------------
#pragma unroll
        for (int m = 0; m < 8; ++m) a[m] = AFRAG(cb, 0, wm * 128 + m * 16 + lcol);
#pragma unroll
        for (int n = 0; n < 2; ++n) b0[n] = BFRAG(cb, 0, wn * 64 + n * 16 + lcol);
        if (pre) ISSUE_HALF(Ags, &Al[nb][0][0]);
        __builtin_amdgcn_s_barrier();
        __builtin_amdgcn_s_setprio(1);
#pragma unroll
        for (int m = 0; m < 8; ++m)
#pragma unroll
            for (int n = 0; n < 2; ++n)
                acc[m][n] = __builtin_amdgcn_mfma_f32_16x16x32_bf16(
                    a[m], b0[n], acc[m][n], 0, 0, 0);
        __builtin_amdgcn_s_setprio(0);

        // ---- phase 1: B(g0) n2-3; issue Bkh0(t+1); force kh1(t) ----------
#pragma unroll
        for (int n = 0; n < 2; ++n) b1[n] = BFRAG(cb, 0, wn * 64 + (2 + n) * 16 + lcol);
        if (pre) {
            ISSUE_HALF(Bgs, &Bl[nb][0][0]);
            asm volatile("s_waitcnt vmcnt(4)" ::: "memory");
        } else {
            asm volatile("s_waitcnt vmcnt(0)" ::: "memory");
        }
        __builtin_amdgcn_s_barrier();
        __builtin_amdgcn_s_setprio(1);
#pragma unroll
        for (int m = 0; m < 8; ++m)
#pragma unroll
            for (int n = 0; n < 2; ++n)
                acc[m][2 + n] = __builtin_amdgcn_mfma_f32_16x16x32_bf16(
                    a[m], b1[n], acc[m][2 + n], 0, 0, 0);
        __builtin_amdgcn_s_setprio(0);

        // ---- phase 2: A(g1), B(g1) n0-1; issue Akh1(t+1) ------------------
#pragma unroll
        for (int m = 0; m < 8; ++m) a[m] = AFRAG(cb, 1, wm * 128 + m * 16 + lcol);
#pragma unroll
        for (int n = 0; n < 2; ++n) b0[n] = BFRAG(cb, 1, wn * 64 + n * 16 + lcol);
        if (pre) ISSUE_HALF(Ags + 64, &Al[nb][1][0]);
        __builtin_amdgcn_s_barrier();
        __builtin_amdgcn_s_setprio(1);
#pragma unroll
        for (int m = 0; m < 8; ++m)
#pragma unroll
            for (int n = 0; n < 2; ++n)
                acc[m][n] = __builtin_amdgcn_mfma_f32_16x16x32_bf16(
                    a[m], b0[n], acc[m][n], 0, 0, 0);
        __builtin_amdgcn_s_setprio(0);

        // ---- phase 3: B(g1) n2-3; issue Bkh1(t+1); force kh0(t+1) --------
#pragma unroll
        for (int n = 0; n < 2; ++n) b1[n] = BFRAG(cb, 1, wn * 64 + (2 + n) * 16 + lcol);
        if (pre) {
            ISSUE_HALF(Bgs + 64, &Bl[nb][1][0]);
            asm volatile("s_waitcnt vmcnt(4)" ::: "memory");
        }
        __builtin_amdgcn_s_barrier();
        __builtin_amdgcn_s_setprio(1);
#pragma unroll
        for (int m = 0; m < 8; ++m)
#pragma unroll
            for (int n = 0; n < 2; ++n)
                acc[m][2 + n] = __builtin_amdgcn_mfma_f32_16x16x32_bf16(
                    a[m], b1[n], acc[m][2 + n], 0, 0, 0);
        __builtin_amdgcn_s_setprio(0);
        __builtin_amdgcn_s_barrier();
    }
#undef ISSUE_HALF
#undef AFRAG
#undef BFRAG

    // ---- epilogue: block-local argmin, plain store ------------------------
    u64* cand = (u64*)Al;   // overlays A buffers (all LDS reads complete)
#pragma unroll
    for (int m = 0; m < 8; ++m) {
#pragma unroll
        for (int j = 0; j < 4; ++j) {
            float bv = 3.4e38f;
            int   bk = 0;
#pragma unroll
            for (int n = 0; n < 4; ++n) {
                const float sc = fmaf(-2.f, acc[m][n][j], Ss[wn * 64 + n * 16 + lcol]);
                const int   kk = (int)n0 + wn * 64 + n * 16 + lcol;
                if (sc < bv) { bv = sc; bk = kk; }     // ascending: ties keep low k
            }
            unsigned sb = __float_as_uint(bv);
            sb = (sb & 0x80000000u) ? ~sb : (sb | 0x80000000u);  // order-preserving
            u64 pk = ((u64)sb << 32) | (unsigned)bk;
#pragma unroll
            for (int mm = 1; mm < 16; mm <<= 1) {
                const u64 o = __shfl_xor(pk, mm);
                pk = (o < pk) ? o : pk;
            }
            if (lcol == 0)
                cand[(wm * 128 + m * 16 + rhi * 4 + j) * 4 + wn] = pk;
        }
    }
    __syncthreads();
    if (tid < 256) {
        const u64* c4 = cand + (size_t)tid * 4;
        u64 pk = c4[0];
        if (c4[1] < pk) pk = c4[1];
        if (c4[2] < pk) pk = c4[2];
        if (c4[3] < pk) pk = c4[3];
        partial[(r0 + tid) * 64 + bn] = pk;
    }
}

// ---------------------------------------------------------------------------
// reduce: per row, min over the 64 col-block partials -> qidx.
// ---------------------------------------------------------------------------
__global__ __launch_bounds__(256) void reduce_kernel(
    const u64* __restrict__ partial, int* __restrict__ qidx)
{
    const int row  = blockIdx.x * 4 + (threadIdx.x >> 6);
    const int lane = threadIdx.x & 63;
    u64 pk = partial[(size_t)row * 64 + lane];
#pragma unroll
    for (int m = 1; m < 64; m <<= 1) {
        const u64 o = __shfl_xor(pk, m);
        pk = (o < pk) ? o : pk;
    }
    if (lane == 0) qidx[row] = (int)(pk & 0xffffffffULL);
}

// ---------------------------------------------------------------------------
// Gather quantized rows + emit indices as float.
// ---------------------------------------------------------------------------
__global__ __launch_bounds__(256) void gather_kernel(
    const float* __restrict__ emb, const int* __restrict__ qidx,
    float* __restrict__ outq, float* __restrict__ outidx)
{
    const int row = blockIdx.x;
    const int d   = threadIdx.x;
    const int k   = qidx[row];
    outq[(size_t)row * D + d] = emb[(size_t)k * D + d];
    if (d == 0) outidx[row] = (float)k;
}

extern "C" void kernel_launch(void* const* d_in, const int* in_sizes, int n_in,
                              void* d_out, int out_size, void* d_ws, size_t ws_size,
                              hipStream_t stream)
{
    const float* z  = (const float*)d_in[0];
    const float* ew = (const float*)d_in[1];
    const float* pw = (const float*)d_in[2];
    const float* pb = (const float*)d_in[3];

    float* out     = (float*)d_out;
    float* out_z   = out;                                  // (B,N,D)
    float* out_emb = out + (size_t)BNROWS * D;             // (K,D)
    float* out_q   = out + 2 * (size_t)BNROWS * D;         // (B,N,D)
    float* out_idx = out + 3 * (size_t)BNROWS * D;         // (B,N) as float

    // ws: sbuf 64KB | qidx 64KB | zhi 8MB | zlo 8MB   (~16.1 MB)
    float*          sbuf = (float*)d_ws;
    int*            qidx = (int*)((char*)d_ws + 65536);
    unsigned short* zhi  = (unsigned short*)((char*)d_ws + 131072);
    unsigned short* zlo  = (unsigned short*)((char*)d_ws + 131072 + 8388608);
    // e-planes live in out_q (16 MB), overwritten by gather afterwards
    unsigned short* ehi  = (unsigned short*)out_q;
    unsigned short* elo  = (unsigned short*)out_q + (size_t)KCB * D;
    // partial argmin table (8 MB) lives in out_z, consumed by reduce_kernel,
    // then overwritten by the late z-memcpy
    u64* partial = (u64*)out_z;

    zsplit_kernel<<<(BNROWS * D) / (256 * 4), 256, 0, stream>>>(z, zhi, zlo);
    proj_kernel<<<(KCB / 64) * 4, 256, 0, stream>>>(ew, pw, pb, out_emb);
    snorm_kernel<<<KCB / 64, 256, 0, stream>>>(out_emb, sbuf, ehi, elo);
    argmin_kernel<<<(BNROWS / 256) * (KCB / 256), 512, 0, stream>>>(
        zhi, zlo, ehi, elo, sbuf, partial);
    reduce_kernel<<<BNROWS / 4, 256, 0, stream>>>(partial, qidx);
    hipMemcpyAsync(out_z, z, (size_t)BNROWS * D * sizeof(float),
                   hipMemcpyDeviceToDevice, stream);
    gather_kernel<<<BNROWS, 256, 0, stream>>>(out_emb, qidx, out_q, out_idx);
}

// Round 6
// 519.160 us; speedup vs baseline: 5.7323x; 1.0238x over previous
//
#include <hip/hip_runtime.h>
#include <hip/hip_bf16.h>

#define D      256
#define KCB    16384
#define BNROWS 16384
#define NT     24          // K-tiles: 768 / 32

typedef __attribute__((ext_vector_type(8))) short short8;   // 8 bf16 = 4 VGPR
typedef __attribute__((ext_vector_type(4))) float f32x4;
typedef unsigned long long u64;

__device__ __forceinline__ void gload_lds16(const void* g, void* l) {
    __builtin_amdgcn_global_load_lds(
        (const __attribute__((address_space(1))) void*)g,
        (__attribute__((address_space(3))) void*)l, 16, 0, 0);
}

__device__ __forceinline__ void bf16split(float x, unsigned short& hi, unsigned short& lo) {
    __hip_bfloat16 h = __float2bfloat16(x);
    float hf = __bfloat162float(h);
    __hip_bfloat16 l = __float2bfloat16(x - hf);
    hi = *(unsigned short*)&h;
    lo = *(unsigned short*)&l;
}

// ---------------------------------------------------------------------------
// z -> (z_hi, z_lo) bf16 planes.
// ---------------------------------------------------------------------------
__global__ __launch_bounds__(256) void zsplit_kernel(
    const float* __restrict__ z,
    unsigned short* __restrict__ zhi, unsigned short* __restrict__ zlo)
{
    const int i = blockIdx.x * 256 + threadIdx.x;
    float4 v = ((const float4*)z)[i];
    ushort4 h, l;
    bf16split(v.x, h.x, l.x);
    bf16split(v.y, h.y, l.y);
    bf16split(v.z, h.z, l.z);
    bf16split(v.w, h.w, l.w);
    ((ushort4*)zhi)[i] = h;
    ((ushort4*)zlo)[i] = l;
}

// ---------------------------------------------------------------------------
// proj: emb = ew @ pw^T + pb as a tiled fp32 GEMM (64x64 tile, LDS pad 65).
// ---------------------------------------------------------------------------
__global__ __launch_bounds__(256) void proj_kernel(
    const float* __restrict__ ew, const float* __restrict__ pw,
    const float* __restrict__ pb, float* __restrict__ emb)
{
    __shared__ float Et[64][65];
    __shared__ float Pt[64][65];
    const int tid = threadIdx.x;
    const int tc  = tid & 15, tr = tid >> 4;
    const int k0  = (blockIdx.x >> 2) * 64;
    const int d0  = (blockIdx.x & 3) * 64;

    float acc[4][4];
#pragma unroll
    for (int a = 0; a < 4; ++a)
#pragma unroll
        for (int b = 0; b < 4; ++b) acc[a][b] = 0.f;

    for (int j0 = 0; j0 < 256; j0 += 64) {
        __syncthreads();
#pragma unroll
        for (int i = 0; i < 4; ++i) {
            const int c = i * 256 + tid;
            const int r = c >> 4, c4 = (c & 15) * 4;
            float4 v = *(const float4*)(ew + (size_t)(k0 + r) * 256 + j0 + c4);
            Et[r][c4 + 0] = v.x; Et[r][c4 + 1] = v.y;
            Et[r][c4 + 2] = v.z; Et[r][c4 + 3] = v.w;
            float4 w = *(const float4*)(pw + (size_t)(d0 + r) * 256 + j0 + c4);
            Pt[r][c4 + 0] = w.x; Pt[r][c4 + 1] = w.y;
            Pt[r][c4 + 2] = w.z; Pt[r][c4 + 3] = w.w;
        }
        __syncthreads();
        for (int j = 0; j < 64; ++j) {
            float ev[4], pv[4];
#pragma unroll
            for (int a = 0; a < 4; ++a) ev[a] = Et[tr * 4 + a][j];
#pragma unroll
            for (int b = 0; b < 4; ++b) pv[b] = Pt[tc * 4 + b][j];
#pragma unroll
            for (int a = 0; a < 4; ++a)
#pragma unroll
                for (int b = 0; b < 4; ++b)
                    acc[a][b] = fmaf(ev[a], pv[b], acc[a][b]);
        }
    }

    const float4 bias = *(const float4*)(pb + d0 + tc * 4);
#pragma unroll
    for (int a = 0; a < 4; ++a) {
        float4 o;
        o.x = acc[a][0] + bias.x; o.y = acc[a][1] + bias.y;
        o.z = acc[a][2] + bias.z; o.w = acc[a][3] + bias.w;
        *(float4*)(emb + (size_t)(k0 + tr * 4 + a) * 256 + d0 + tc * 4) = o;
    }
}

// ---------------------------------------------------------------------------
// snorm: s[k] = ||emb[k]||^2 + bf16 hi/lo planes of emb.
// ---------------------------------------------------------------------------
__global__ __launch_bounds__(256) void snorm_kernel(
    const float* __restrict__ emb, float* __restrict__ s,
    unsigned short* __restrict__ ehi, unsigned short* __restrict__ elo)
{
    const int tid = threadIdx.x;
    const int row = blockIdx.x * 64 + (tid >> 2);
    const int qd  = tid & 3;
    const size_t base = (size_t)row * 256;
    float sq = 0.f;
#pragma unroll
    for (int j = 0; j < 16; ++j) {
        const int off = qd * 4 + j * 16;
        float4 v = *(const float4*)(emb + base + off);
        ushort4 h, l;
        bf16split(v.x, h.x, l.x);
        bf16split(v.y, h.y, l.y);
        bf16split(v.z, h.z, l.z);
        bf16split(v.w, h.w, l.w);
        *(ushort4*)(ehi + base + off) = h;
        *(ushort4*)(elo + base + off) = l;
        sq = fmaf(v.x, v.x, fmaf(v.y, v.y, fmaf(v.z, v.z, fmaf(v.w, v.w, sq))));
    }
    sq += __shfl_xor(sq, 1);
    sq += __shfl_xor(sq, 2);
    if (qd == 0) s[row] = sq;
}

// ---------------------------------------------------------------------------
// argmin v6: 128x256 tile, 8 waves (2Mx4N, 64x64 out each), BK=32,
// TRIPLE-buffered LDS (73 KB) + __launch_bounds__(512,4) -> 2 blocks/CU.
// Per tile: {read b[4] | issue A,B(t+2) | 4x(read a, 4 MFMA) | vmcnt(3) | bar}
//   - single barrier per tile (WAR on buf[(t+2)%3] covered by tile t-1's
//     barrier: its reads finished before t-1's MFMA which precede that bar)
//   - vmcnt(3): t+1's 3 loads (issued at t-1) forced done; t+2's stay in
//     flight -> 2-tile (~2500 cyc) staging slack, never drained mid-loop.
// LDS layout: two 64-B K-slice rows packed per 128-B LDS row:
//   l = row>>1, q = ((row&1)*4 + rhi) ^ (l&7), byte = l*128 + q*16
//   -> identical bank pattern to the rounds-2..4 layout (measured 0 conflicts)
//   Global source pre-swizzled with the same involution (linear gload dest).
// Epilogue: block-local LDS combine -> partial[row][64]; no global atomics.
// ---------------------------------------------------------------------------
__global__ __launch_bounds__(512, 4) void argmin_kernel(
    const unsigned short* __restrict__ zhi, const unsigned short* __restrict__ zlo,
    const unsigned short* __restrict__ ehi, const unsigned short* __restrict__ elo,
    const float* __restrict__ s, u64* __restrict__ partial)
{
    __shared__ alignas(16) unsigned short Al[3][4096];   // 3 x (64 rows x 128B)
    __shared__ alignas(16) unsigned short Bl[3][8192];   // 3 x (128 rows x 128B)
    __shared__ float Ss[256];

    const int tid  = threadIdx.x;
    const int lane = tid & 63;
    const int wid  = tid >> 6;
    const int wm   = wid >> 2;      // 0..1: rows wm*64..+63
    const int wn   = wid & 3;       // 0..3: cols wn*64..+63
    const int lcol = lane & 15;
    const int rhi  = lane >> 4;     // K-chunk 0..3 (8 bf16 each)

    const int bm = blockIdx.x >> 6;        // natural order
    const int bn = blockIdx.x & 63;
    const size_t r0 = (size_t)bm * 128;
    const size_t n0 = (size_t)bn * 256;

    if (tid < 256) Ss[tid] = s[n0 + tid];

    // stage: LDS dest linear in 16B slots; global source pre-swizzled.
    // slot c: l=c>>3, q=c&7, u=q^(l&7) -> logical row 2l+(u>>2), subchunk u&3
#define ISSUE_A(srcb, buf)                                                    \
    {                                                                         \
        const int c = wid * 64 + lane;          /* 512 slots */               \
        const int l = c >> 3, q = c & 7;                                      \
        const int u = q ^ (l & 7);                                            \
        gload_lds16((srcb) + (size_t)(2 * l + (u >> 2)) * 512 + ((u & 3) << 4), \
                    (void*)(&Al[buf][c * 8]));                                \
    }
#define ISSUE_B(srcb, buf)                                                    \
    {                                                                         \
        _Pragma("unroll")                                                     \
        for (int i = 0; i < 2; ++i) {                                         \
            const int c = wid * 128 + i * 64 + lane;   /* 1024 slots */       \
            const int l = c >> 3, q = c & 7;                                  \
            const int u = q ^ (l & 7);                                        \
            gload_lds16((srcb) + (size_t)(2 * l + (u >> 2)) * 512 + ((u & 3) << 4), \
                        (void*)(&Bl[buf][c * 8]));                            \
        }                                                                     \
    }
#define AFRAG(buf, row) (*(const short8*)(&Al[buf][((row) >> 1) * 64 + \
        (((((row) & 1) * 4 + rhi) ^ (((row) >> 1) & 7)) << 3)]))
#define BFRAG(buf, row) (*(const short8*)(&Bl[buf][((row) >> 1) * 64 + \
        (((((row) & 1) * 4 + rhi) ^ (((row) >> 1) & 7)) << 3)]))

    // prologue: issue tiles 0 and 1 (plane 0: zh, eh)
    {
        const char* A0 = (const char*)zhi + r0 * 512;
        const char* B0 = (const char*)ehi + n0 * 512;
        ISSUE_A(A0, 0);
        ISSUE_B(B0, 0);
        ISSUE_A(A0 + 64, 1);
        ISSUE_B(B0 + 64, 1);
    }
    asm volatile("s_waitcnt vmcnt(3) lgkmcnt(0)" ::: "memory");  // tile0 + Ss in
    __builtin_amdgcn_s_barrier();

    f32x4 acc[4][4];
    const f32x4 zero = {0.f, 0.f, 0.f, 0.f};
#pragma unroll
    for (int m = 0; m < 4; ++m)
#pragma unroll
        for (int n = 0; n < 4; ++n) acc[m][n] = zero;

    for (int t = 0; t < NT; ++t) {
        const int bt = t % 3;
        const int b2 = (t + 2) % 3;
        const int t2 = t + 2;
        const bool pre = (t2 < NT);

        short8 bq[4];
#pragma unroll
        for (int n = 0; n < 4; ++n)
            bq[n] = BFRAG(bt, wn * 64 + n * 16 + lcol);

        if (pre) {
            const int pp = t2 >> 3;   // plane: 0 zh*eh, 1 zl*eh, 2 zh*el
            const char* Ags = (const char*)((pp == 1) ? zlo : zhi)
                              + r0 * 512 + (size_t)(t2 & 7) * 64;
            const char* Bgs = (const char*)((pp == 2) ? elo : ehi)
                              + n0 * 512 + (size_t)(t2 & 7) * 64;
            ISSUE_A(Ags, b2);
            ISSUE_B(Bgs, b2);
        }

        __builtin_amdgcn_s_setprio(1);
#pragma unroll
        for (int m = 0; m < 4; ++m) {
            const short8 am = AFRAG(bt, wm * 64 + m * 16 + lcol);
#pragma unroll
            for (int n = 0; n < 4; ++n)
                acc[m][n] = __builtin_amdgcn_mfma_f32_16x16x32_bf16(
                    am, bq[n], acc[m][n], 0, 0, 0);
        }
        __builtin_amdgcn_s_setprio(0);

        if (pre)
            asm volatile("s_waitcnt vmcnt(3)" ::: "memory");   // t+1 resident
        else if (t + 1 < NT)
            asm volatile("s_waitcnt vmcnt(0)" ::: "memory");
        __builtin_amdgcn_s_barrier();
    }
#undef ISSUE_A
#undef ISSUE_B
#undef AFRAG
#undef BFRAG

    // ---- epilogue: block-local argmin, plain store ------------------------
    u64* cand = (u64*)Al;   // 4 KB overlay; all LDS reads retired pre-barrier
#pragma unroll
    for (int m = 0; m < 4; ++m) {
#pragma unroll
        for (int j = 0; j < 4; ++j) {
            float bv = 3.4e38f;
            int   bk = 0;
#pragma unroll
            for (int n = 0; n < 4; ++n) {
                const float sc = fmaf(-2.f, acc[m][n][j], Ss[wn * 64 + n * 16 + lcol]);
                const int   kk = (int)n0 + wn * 64 + n * 16 + lcol;
                if (sc < bv) { bv = sc; bk = kk; }     // ascending: ties keep low k
            }
            unsigned sb = __float_as_uint(bv);
            sb = (sb & 0x80000000u) ? ~sb : (sb | 0x80000000u);  // order-preserving
            u64 pk = ((u64)sb << 32) | (unsigned)bk;
#pragma unroll
            for (int mm = 1; mm < 16; mm <<= 1) {
                const u64 o = __shfl_xor(pk, mm);
                pk = (o < pk) ? o : pk;
            }
            if (lcol == 0)
                cand[(wm * 64 + m * 16 + rhi * 4 + j) * 4 + wn] = pk;
        }
    }
    __syncthreads();
    if (tid < 128) {
        const u64* c4 = cand + (size_t)tid * 4;
        u64 pk = c4[0];
        if (c4[1] < pk) pk = c4[1];
        if (c4[2] < pk) pk = c4[2];
        if (c4[3] < pk) pk = c4[3];
        partial[(r0 + tid) * 64 + bn] = pk;
    }
}

// ---------------------------------------------------------------------------
// reduce: per row, min over the 64 col-block partials -> qidx.
// ---------------------------------------------------------------------------
__global__ __launch_bounds__(256) void reduce_kernel(
    const u64* __restrict__ partial, int* __restrict__ qidx)
{
    const int row  = blockIdx.x * 4 + (threadIdx.x >> 6);
    const int lane = threadIdx.x & 63;
    u64 pk = partial[(size_t)row * 64 + lane];
#pragma unroll
    for (int m = 1; m < 64; m <<= 1) {
        const u64 o = __shfl_xor(pk, m);
        pk = (o < pk) ? o : pk;
    }
    if (lane == 0) qidx[row] = (int)(pk & 0xffffffffULL);
}

// ---------------------------------------------------------------------------
// Gather quantized rows + emit indices as float.
// ---------------------------------------------------------------------------
__global__ __launch_bounds__(256) void gather_kernel(
    const float* __restrict__ emb, const int* __restrict__ qidx,
    float* __restrict__ outq, float* __restrict__ outidx)
{
    const int row = blockIdx.x;
    const int d   = threadIdx.x;
    const int k   = qidx[row];
    outq[(size_t)row * D + d] = emb[(size_t)k * D + d];
    if (d == 0) outidx[row] = (float)k;
}

extern "C" void kernel_launch(void* const* d_in, const int* in_sizes, int n_in,
                              void* d_out, int out_size, void* d_ws, size_t ws_size,
                              hipStream_t stream)
{
    const float* z  = (const float*)d_in[0];
    const float* ew = (const float*)d_in[1];
    const float* pw = (const float*)d_in[2];
    const float* pb = (const float*)d_in[3];

    float* out     = (float*)d_out;
    float* out_z   = out;                                  // (B,N,D)
    float* out_emb = out + (size_t)BNROWS * D;             // (K,D)
    float* out_q   = out + 2 * (size_t)BNROWS * D;         // (B,N,D)
    float* out_idx = out + 3 * (size_t)BNROWS * D;         // (B,N) as float

    // ws: sbuf 64KB | qidx 64KB | zhi 8MB | zlo 8MB   (~16.1 MB)
    float*          sbuf = (float*)d_ws;
    int*            qidx = (int*)((char*)d_ws + 65536);
    unsigned short* zhi  = (unsigned short*)((char*)d_ws + 131072);
    unsigned short* zlo  = (unsigned short*)((char*)d_ws + 131072 + 8388608);
    // e-planes live in out_q (16 MB), overwritten by gather afterwards
    unsigned short* ehi  = (unsigned short*)out_q;
    unsigned short* elo  = (unsigned short*)out_q + (size_t)KCB * D;
    // partial argmin table (8 MB) lives in out_z, consumed by reduce_kernel,
    // then overwritten by the late z-memcpy
    u64* partial = (u64*)out_z;

    zsplit_kernel<<<(BNROWS * D) / (256 * 4), 256, 0, stream>>>(z, zhi, zlo);
    proj_kernel<<<(KCB / 64) * 4, 256, 0, stream>>>(ew, pw, pb, out_emb);
    snorm_kernel<<<KCB / 64, 256, 0, stream>>>(out_emb, sbuf, ehi, elo);
    argmin_kernel<<<(BNROWS / 128) * (KCB / 256), 512, 0, stream>>>(
        zhi, zlo, ehi, elo, sbuf, partial);
    reduce_kernel<<<BNROWS / 4, 256, 0, stream>>>(partial, qidx);
    hipMemcpyAsync(out_z, z, (size_t)BNROWS * D * sizeof(float),
                   hipMemcpyDeviceToDevice, stream);
    gather_kernel<<<BNROWS, 256, 0, stream>>>(out_emb, qidx, out_q, out_idx);
}